// Round 7
// baseline (180.426 us; speedup 1.0000x reference)
//
#include <hip/hip_runtime.h>
#include <math.h>

#define D_MODEL 1024
#define N_STATE 64
#define L_LEN   2048

typedef __attribute__((ext_vector_type(2))) float f32x2;

// ---------------------------------------------------------------------------
// Kernel A: per-(d,n) parameter setup in double precision. One thread per
// (d,n) pair, 65536 threads, fully parallel. Writes 8 packed floats per
// (d,n): {th_hi, th_lo, ph, la_hi} {la_lo, lw, 2Re(Abar^16), |Abar^16|^2}.
// th/la split hi(multiple of 2^-12)/lo so l*hi is exact fp32 for l < 2^11.
// ---------------------------------------------------------------------------
__global__ __launch_bounds__(256) void s4d_setup(
    const float* __restrict__ A_real, const float* __restrict__ A_imag,
    const float* __restrict__ B, const float* __restrict__ C,
    const float* __restrict__ log_dt, float* __restrict__ par)
{
    const int id = blockIdx.x * 256 + threadIdx.x;   // [0, 65536)
    const int d = id >> 6;
    const int n = id & 63;

    const double dt = exp((double)log_dt[d]);
    const double zr = 0.5 * dt * (double)A_real[n];
    const double zi = 0.5 * dt * (double)A_imag[n];
    const double dr = 1.0 - zr, di = -zi;
    const double inv = 1.0 / (dr*dr + di*di);
    const double nr = 1.0 + zr, ni = zi;
    const double sr = (nr*dr + ni*di) * inv;      // Abar
    const double si = (ni*dr - nr*di) * inv;
    const double dtB = dt * (double)B[n*D_MODEL + d];
    const double br = dtB * dr * inv;
    const double bi = dtB * zi * inv;
    const double cr = (double)C[(d*N_STATE + n)*2 + 0];
    const double ci = (double)C[(d*N_STATE + n)*2 + 1];
    const double wr = cr*br - ci*bi;              // w = Cc * Bbar
    const double wi = cr*bi + ci*br;

    const double INV2PI = 0.15915494309189535;
    const double threv = atan2(si, sr) * INV2PI;
    const double la    = 0.5 * log2(sr*sr + si*si);
    const double w2    = wr*wr + wi*wi;
    const double lw    = 0.5 * log2(fmax(w2, 1e-60));
    const double phrev = atan2(wi, wr) * INV2PI;

    const double th_hi = nearbyint(threv * 4096.0) * (1.0 / 4096.0);
    const double la_hi = nearbyint(la    * 4096.0) * (1.0 / 4096.0);

    // Abar^16 by 4 complex squarings in double:
    double pr = sr, pq = si;
    #pragma unroll
    for (int k = 0; k < 4; ++k) {
        double a2 = pr*pr - pq*pq;
        double b2 = 2.0*pr*pq;
        pr = a2; pq = b2;
    }

    float4 p0, p1;
    p0.x = (float)th_hi;
    p0.y = (float)(threv - th_hi);
    p0.z = (float)phrev;
    p0.w = (float)la_hi;
    p1.x = (float)(la - la_hi);
    p1.y = (float)lw;
    p1.z = (float)(2.0 * pr);            // 2*Re(Abar^16)
    p1.w = (float)(pr*pr + pq*pq);       // |Abar^16|^2
    float4* o = (float4*)(par + (size_t)id * 8);
    o[0] = p0;
    o[1] = p1;
}

// Closed-form single-term eval (validated: absmax 0.0039):
// |w| * |Abar|^l * cos(2*pi*(l*theta + phi))
__device__ __forceinline__ float eval_term(float lf,
                                           float th_hi, float th_lo, float ph0,
                                           float la_hi, float la_lo, float lw) {
    float amp = exp2f(fmaf(lf, la_hi, fmaf(lf, la_lo, lw)));
    float f1  = __builtin_amdgcn_fractf(lf * th_hi);           // exact product
    float ph  = __builtin_amdgcn_fractf(f1 + fmaf(lf, th_lo, ph0));
    return amp * __builtin_amdgcn_cosf(ph);                    // cos(2*pi*x)
}

// DPP quad-perm helper. 0xB1 = xor1, 0x4E = xor2 within quad. VALU-rate.
template <int CTRL>
__device__ __forceinline__ float dpp_perm_f32(float x) {
    return __int_as_float(__builtin_amdgcn_update_dpp(
        0, __float_as_int(x), CTRL, 0xF, 0xF, true));
}

// ---------------------------------------------------------------------------
// Kernel B: one block per d (4 waves; wave w owns l in [512w, 512w+512)).
// Lane split: q = lane&3 (intra-quad state quartet), g = lane>>2 (l offset).
// Params staged to LDS by the whole block (one coalesced float2 per thread)
// -- removes the per-lane serial global-load latency chain found in R6.
// Chains packed in pairs (f32x2) to court v_pk_{mul,add,fma}_f32.
// Recurrence per pair: y_{i+1} = 2Re(A^16)*y_i - |A^16|^2*y_{i-1}.
// Cross-lane reduce = 2 DPP quad-perm adds; stores batched 4 steps (256B).
// REPS>1 = profiling decoy: step-loop repeated (state keeps evolving -> no
// CSE; decays to zero, VALU timing data-independent), writes to ws region.
// ---------------------------------------------------------------------------
template <int REPS>
__global__ __launch_bounds__(256) void s4d_main(
    const float* __restrict__ par, const float* __restrict__ Dv,
    float* __restrict__ outbase)
{
    __shared__ __align__(16) float s_par[N_STATE * 8];   // 2 KB

    const int d = blockIdx.x;
    const int t = threadIdx.x;

    // cooperative param stage: 256 threads x 8B = 2KB, fully coalesced
    ((float2*)s_par)[t] = ((const float2*)(par + (size_t)d * (N_STATE * 8)))[t];
    __syncthreads();

    const int wv   = t >> 6;
    const int lane = t & 63;
    const int q    = lane & 3;
    const int g    = lane >> 2;
    const int lbase = wv * 512 + g;
    const float lf0 = (float)lbase;
    const float lf1 = (float)(lbase + 16);

    f32x2 y0p[8], y1p[8], arp[8], amn[8];
    #pragma unroll
    for (int cp = 0; cp < 8; ++cp) {
        const int n0 = (cp << 3) | q;        // chain 2cp   -> n = 8cp+q
        const int n1 = n0 | 4;               // chain 2cp+1 -> n = 8cp+4+q
        const float4 a0 = *(const float4*)&s_par[n0 * 8];
        const float4 b0 = *(const float4*)&s_par[n0 * 8 + 4];
        const float4 a1 = *(const float4*)&s_par[n1 * 8];
        const float4 b1 = *(const float4*)&s_par[n1 * 8 + 4];
        f32x2 v;
        v.x = b0.z;  v.y = b1.z;  arp[cp] = v;
        v.x = -b0.w; v.y = -b1.w; amn[cp] = v;      // negated |A^16|^2
        v.x = eval_term(lf0, a0.x, a0.y, a0.z, a0.w, b0.x, b0.y);
        v.y = eval_term(lf0, a1.x, a1.y, a1.z, a1.w, b1.x, b1.y);
        y0p[cp] = v;
        v.x = eval_term(lf1, a0.x, a0.y, a0.z, a0.w, b0.x, b0.y);
        v.y = eval_term(lf1, a1.x, a1.y, a1.z, a1.w, b1.x, b1.y);
        y1p[cp] = v;
    }

    const float dval = Dv[d];
    // lane's slot within each 64-float batch block: g + 16q
    float* __restrict__ op = outbase + (size_t)d * L_LEN + (wv << 9) + g + (q << 4);

    #pragma unroll 1
    for (int rep = 0; rep < REPS; ++rep) {
        #pragma unroll
        for (int j = 0; j < 8; ++j) {        // 8 batches x 4 steps = 32 steps
            float S0, S1, S2, S3;
            #pragma unroll
            for (int s = 0; s < 4; ++s) {
                // packed tree-sum of 16 chains (value at l = lbase+16*(4j+s))
                f32x2 r40 = y0p[0] + y0p[1];
                f32x2 r41 = y0p[2] + y0p[3];
                f32x2 r42 = y0p[4] + y0p[5];
                f32x2 r43 = y0p[6] + y0p[7];
                f32x2 r2a = r40 + r41, r2b = r42 + r43;
                f32x2 r1  = r2a + r2b;
                float sum = r1.x + r1.y;
                // intra-quad butterfly over q (no DS ops):
                sum += dpp_perm_f32<0xB1>(sum);
                sum += dpp_perm_f32<0x4E>(sum);
                if      (s == 0) S0 = sum;
                else if (s == 1) S1 = sum;
                else if (s == 2) S2 = sum;
                else             S3 = sum;
                // packed advance: yn = ar*y1 + (-am)*y0
                #pragma unroll
                for (int cp = 0; cp < 8; ++cp) {
                    f32x2 tm = amn[cp] * y0p[cp];
                    f32x2 yn = __builtin_elementwise_fma(arp[cp], y1p[cp], tm);
                    y0p[cp] = y1p[cp];
                    y1p[cp] = yn;
                }
            }
            // lane stores step s=q (explicit cndmask selects, reg-resident):
            float t0 = (q & 1) ? S1 : S0;
            float t1 = (q & 1) ? S3 : S2;
            float v  = (q & 2) ? t1 : t0;
            if (j == 0 && t == 0) v += dval;  // D * delta[0]
            op[j << 6] = v;                   // 256B fully-coalesced store
        }
    }
}

extern "C" void kernel_launch(void* const* d_in, const int* in_sizes, int n_in,
                              void* d_out, int out_size, void* d_ws, size_t ws_size,
                              hipStream_t stream) {
    const float* A_real = (const float*)d_in[0];
    const float* A_imag = (const float*)d_in[1];
    const float* B      = (const float*)d_in[2];
    const float* C      = (const float*)d_in[3];
    const float* Dv     = (const float*)d_in[4];
    const float* log_dt = (const float*)d_in[5];
    float* out = (float*)d_out;
    float* par = (float*)d_ws;                          // 2 MB at ws base
    float* decoy_out = (float*)d_ws + (4u << 20);       // +16 MB, uses 8 MB
    (void)in_sizes; (void)n_in; (void)ws_size; (void)out_size;

    s4d_setup<<<dim3(D_MODEL * N_STATE / 256), dim3(256), 0, stream>>>(
        A_real, A_imag, B, C, log_dt, par);
    // Profiling decoy (this round only): 16x step-loop -> lands in rocprof
    // top-5 with counters; phase split: t=(decoy-main)/15, s=main-t.
    s4d_main<16><<<dim3(D_MODEL), dim3(256), 0, stream>>>(par, Dv, decoy_out);
    // Real output:
    s4d_main<1><<<dim3(D_MODEL), dim3(256), 0, stream>>>(par, Dv, out);
}

// Round 8
// 84.522 us; speedup vs baseline: 2.1347x; 2.1347x over previous
//
#include <hip/hip_runtime.h>
#include <math.h>

#define D_MODEL 1024
#define N_STATE 64
#define L_LEN   2048
#define PAR_STRIDE 12   // floats per (d,n)

// ---------------------------------------------------------------------------
// Kernel A: per-(d,n) parameter setup in double precision. One thread per
// (d,n) pair, 65536 threads, fully parallel. Writes 12 packed floats:
//  {th_hi, th_lo, ph, la_hi} {la_lo, lw, 2Re(A16), |A16|^2} {Re(A16), Im(A16), -, -}
// th/la split hi(multiple of 2^-12)/lo so l*hi is exact fp32 for l < 2^11.
// ---------------------------------------------------------------------------
__global__ __launch_bounds__(256) void s4d_setup(
    const float* __restrict__ A_real, const float* __restrict__ A_imag,
    const float* __restrict__ B, const float* __restrict__ C,
    const float* __restrict__ log_dt, float* __restrict__ par)
{
    const int id = blockIdx.x * 256 + threadIdx.x;   // [0, 65536)
    const int d = id >> 6;
    const int n = id & 63;

    const double dt = exp((double)log_dt[d]);
    const double zr = 0.5 * dt * (double)A_real[n];
    const double zi = 0.5 * dt * (double)A_imag[n];
    const double dr = 1.0 - zr, di = -zi;
    const double inv = 1.0 / (dr*dr + di*di);
    const double nr = 1.0 + zr, ni = zi;
    const double sr = (nr*dr + ni*di) * inv;      // Abar
    const double si = (ni*dr - nr*di) * inv;
    const double dtB = dt * (double)B[n*D_MODEL + d];
    const double br = dtB * dr * inv;
    const double bi = dtB * zi * inv;
    const double cr = (double)C[(d*N_STATE + n)*2 + 0];
    const double ci = (double)C[(d*N_STATE + n)*2 + 1];
    const double wr = cr*br - ci*bi;              // w = Cc * Bbar
    const double wi = cr*bi + ci*br;

    const double INV2PI = 0.15915494309189535;
    const double threv = atan2(si, sr) * INV2PI;
    const double la    = 0.5 * log2(sr*sr + si*si);
    const double w2    = wr*wr + wi*wi;
    const double lw    = 0.5 * log2(fmax(w2, 1e-60));
    const double phrev = atan2(wi, wr) * INV2PI;

    const double th_hi = nearbyint(threv * 4096.0) * (1.0 / 4096.0);
    const double la_hi = nearbyint(la    * 4096.0) * (1.0 / 4096.0);

    // Abar^16 by 4 complex squarings in double:
    double pr = sr, pq = si;
    #pragma unroll
    for (int k = 0; k < 4; ++k) {
        double a2 = pr*pr - pq*pq;
        double b2 = 2.0*pr*pq;
        pr = a2; pq = b2;
    }

    float4 p0, p1, p2;
    p0.x = (float)th_hi;
    p0.y = (float)(threv - th_hi);
    p0.z = (float)phrev;
    p0.w = (float)la_hi;
    p1.x = (float)(la - la_hi);
    p1.y = (float)lw;
    p1.z = (float)(2.0 * pr);            // 2*Re(A16)
    p1.w = (float)(pr*pr + pq*pq);       // |A16|^2
    p2.x = (float)pr;                    // Re(A16)
    p2.y = (float)pq;                    // Im(A16)
    p2.z = 0.0f; p2.w = 0.0f;
    float4* o = (float4*)(par + (size_t)id * PAR_STRIDE);
    o[0] = p0;
    o[1] = p1;
    o[2] = p2;
}

// DPP quad-perm helper. 0xB1 = xor1, 0x4E = xor2 within quad. VALU-rate.
template <int CTRL>
__device__ __forceinline__ float dpp_perm_f32(float x) {
    return __int_as_float(__builtin_amdgcn_update_dpp(
        0, __float_as_int(x), CTRL, 0xF, 0xF, true));
}

// ---------------------------------------------------------------------------
// Kernel B: one block per d (4 waves; wave w owns l in [512w, 512w+512)).
// Lane split: q = lane&3 (intra-quad state group), g = lane>>2 (l offset).
// Params staged to LDS cooperatively (R7: removes seed global-latency chain).
// Seed: ONE closed-form complex eval per chain (exp2 + sincos) gives
// wtil = w*Abar^lbase; y0 = Re(wtil), y1 = Re(wtil*A16) = zr*pr - zi*pi.
// Recurrence: y_{i+1} = 2Re(A16)*y_i - |A16|^2*y_{i-1}  (stride-16 in l).
// Cross-lane reduce = 2 DPP quad-perm adds; stores batched 4 steps (256B).
// ---------------------------------------------------------------------------
__global__ __launch_bounds__(256) void s4d_main(
    const float* __restrict__ par, const float* __restrict__ Dv,
    float* __restrict__ out)
{
    __shared__ __align__(16) float s_par[N_STATE * PAR_STRIDE];   // 3 KB

    const int d = blockIdx.x;
    const int t = threadIdx.x;

    // cooperative param stage: 768 floats, 3 coalesced dwords per thread
    {
        const float* gsrc = par + (size_t)d * (N_STATE * PAR_STRIDE);
        s_par[t]       = gsrc[t];
        s_par[t + 256] = gsrc[t + 256];
        s_par[t + 512] = gsrc[t + 512];
    }
    __syncthreads();

    const int wv   = t >> 6;
    const int lane = t & 63;
    const int q    = lane & 3;
    const int g    = lane >> 2;
    const int lbase = wv * 512 + g;
    const float lf0 = (float)lbase;

    float y0[16], y1[16], ar[16], amn[16];
    #pragma unroll
    for (int c = 0; c < 16; ++c) {
        const int n = (c << 2) | q;
        const float4 a  = *(const float4*)&s_par[n * PAR_STRIDE];
        const float4 b  = *(const float4*)&s_par[n * PAR_STRIDE + 4];
        const float2 cc = *(const float2*)&s_par[n * PAR_STRIDE + 8];
        ar[c]  = b.z;
        amn[c] = -b.w;                                   // -|A16|^2
        // amplitude = exp2(l*la + lw), la split hi/lo (exact hi product)
        float amp = exp2f(fmaf(lf0, a.w, fmaf(lf0, b.x, b.y)));
        // phase in revolutions
        float f1 = __builtin_amdgcn_fractf(lf0 * a.x);   // exact product
        float ph = __builtin_amdgcn_fractf(f1 + fmaf(lf0, a.y, a.z));
        float zr = amp * __builtin_amdgcn_cosf(ph);      // Re(wtil)
        float zi = amp * __builtin_amdgcn_sinf(ph);      // Im(wtil)
        y0[c] = zr;
        y1[c] = fmaf(zr, cc.x, -(zi * cc.y));            // Re(wtil*A16)
    }

    const float dval = Dv[d];
    // lane's slot within each 64-float batch block: g + 16q
    float* __restrict__ op = out + (size_t)d * L_LEN + (wv << 9) + g + (q << 4);

    #pragma unroll
    for (int j = 0; j < 8; ++j) {            // 8 batches x 4 steps = 32 steps
        float S0, S1, S2, S3;
        #pragma unroll
        for (int s = 0; s < 4; ++s) {
            // tree-sum this lane's 16 chains (value at l = lbase + 16*(4j+s))
            float r8[8];
            #pragma unroll
            for (int k = 0; k < 8; ++k) r8[k] = y0[2*k] + y0[2*k+1];
            float r4a = r8[0] + r8[1], r4b = r8[2] + r8[3];
            float r4c = r8[4] + r8[5], r4d = r8[6] + r8[7];
            float sum = (r4a + r4b) + (r4c + r4d);
            // intra-quad butterfly over q (VALU-rate DPP, no DS ops):
            sum += dpp_perm_f32<0xB1>(sum);
            sum += dpp_perm_f32<0x4E>(sum);
            if      (s == 0) S0 = sum;
            else if (s == 1) S1 = sum;
            else if (s == 2) S2 = sum;
            else             S3 = sum;
            // advance all chains: y_{i+2} = ar*y_{i+1} + amn*y_i
            #pragma unroll
            for (int c = 0; c < 16; ++c) {
                float yn = fmaf(ar[c], y1[c], amn[c] * y0[c]);
                y0[c] = y1[c];
                y1[c] = yn;
            }
        }
        // lane stores step s=q of this batch (cndmask selects, reg-resident):
        float t0 = (q & 1) ? S1 : S0;
        float t1 = (q & 1) ? S3 : S2;
        float v  = (q & 2) ? t1 : t0;
        if (j == 0 && t == 0) v += dval;     // D * delta[0]
        op[j << 6] = v;                      // 256B fully-coalesced store
    }
}

extern "C" void kernel_launch(void* const* d_in, const int* in_sizes, int n_in,
                              void* d_out, int out_size, void* d_ws, size_t ws_size,
                              hipStream_t stream) {
    const float* A_real = (const float*)d_in[0];
    const float* A_imag = (const float*)d_in[1];
    const float* B      = (const float*)d_in[2];
    const float* C      = (const float*)d_in[3];
    const float* Dv     = (const float*)d_in[4];
    const float* log_dt = (const float*)d_in[5];
    float* out = (float*)d_out;
    float* par = (float*)d_ws;               // 1024*64*12 floats = 3 MB
    (void)in_sizes; (void)n_in; (void)ws_size; (void)out_size;

    s4d_setup<<<dim3(D_MODEL * N_STATE / 256), dim3(256), 0, stream>>>(
        A_real, A_imag, B, C, log_dt, par);
    s4d_main<<<dim3(D_MODEL), dim3(256), 0, stream>>>(par, Dv, out);
}

// Round 9
// 79.429 us; speedup vs baseline: 2.2715x; 1.0641x over previous
//
#include <hip/hip_runtime.h>
#include <math.h>

#define D_MODEL 1024
#define N_STATE 64
#define L_LEN   2048
#define PAR_STRIDE 8

typedef __attribute__((ext_vector_type(8))) short  short8;   // 8 bf16 (4 VGPR)
typedef __attribute__((ext_vector_type(4))) float  f32x4;

// ---------------------------------------------------------------------------
// Kernel A: per-(d,n) parameter setup in f64. One thread per (d,n), 65536
// threads. Writes {th_hi, th_lo, ph, la_hi, la_lo, lw, 0, 0} per (d,n).
// th/la split hi(multiple of 2^-12)/lo so l*hi is exact fp32 for l < 2^11.
// ---------------------------------------------------------------------------
__global__ __launch_bounds__(256) void s4d_setup(
    const float* __restrict__ A_real, const float* __restrict__ A_imag,
    const float* __restrict__ B, const float* __restrict__ C,
    const float* __restrict__ log_dt, float* __restrict__ par)
{
    const int id = blockIdx.x * 256 + threadIdx.x;   // [0, 65536)
    const int d = id >> 6;
    const int n = id & 63;

    const double dt = exp((double)log_dt[d]);
    const double zr = 0.5 * dt * (double)A_real[n];
    const double zi = 0.5 * dt * (double)A_imag[n];
    const double dr = 1.0 - zr, di = -zi;
    const double inv = 1.0 / (dr*dr + di*di);
    const double nr = 1.0 + zr, ni = zi;
    const double sr = (nr*dr + ni*di) * inv;      // Abar
    const double si = (ni*dr - nr*di) * inv;
    const double dtB = dt * (double)B[n*D_MODEL + d];
    const double br = dtB * dr * inv;
    const double bi = dtB * zi * inv;
    const double cr = (double)C[(d*N_STATE + n)*2 + 0];
    const double ci = (double)C[(d*N_STATE + n)*2 + 1];
    const double wr = cr*br - ci*bi;              // w = Cc * Bbar
    const double wi = cr*bi + ci*br;

    const double INV2PI = 0.15915494309189535;
    const double threv = atan2(si, sr) * INV2PI;
    const double la    = 0.5 * log2(sr*sr + si*si);
    const double w2    = wr*wr + wi*wi;
    const double lw    = 0.5 * log2(fmax(w2, 1e-60));
    const double phrev = atan2(wi, wr) * INV2PI;

    const double th_hi = nearbyint(threv * 4096.0) * (1.0 / 4096.0);
    const double la_hi = nearbyint(la    * 4096.0) * (1.0 / 4096.0);

    float4 p0, p1;
    p0.x = (float)th_hi;
    p0.y = (float)(threv - th_hi);
    p0.z = (float)phrev;
    p0.w = (float)la_hi;
    p1.x = (float)(la - la_hi);
    p1.y = (float)lw;
    p1.z = 0.0f;
    p1.w = 0.0f;
    float4* o = (float4*)(par + (size_t)id * PAR_STRIDE);
    o[0] = p0;
    o[1] = p1;
}

// bf16 round-to-nearest-even (manual, branch-free)
__device__ __forceinline__ unsigned short bf16_rne(float x) {
    unsigned int u = __float_as_uint(x);
    return (unsigned short)((u + 0x7FFFu + ((u >> 16) & 1u)) >> 16);
}
__device__ __forceinline__ float bf16_f(unsigned short h) {
    return __uint_as_float((unsigned int)h << 16);
}

// ---------------------------------------------------------------------------
// Kernel B: one block per d. l = 64a + b, a in [0,32), b in [0,64).
//   K[d,l] = sum_n Re(U[n,b] * V[n,a]),  U = w*Abar^b,  V = Abar^(64a).
// Per d: D[a][b] = sum_n V[n,a]*U[n,b] via 6 bf16 hi/lo-split MFMA products
// (lo*lo dropped; -Im*Im folded by negating Ui at split time).
// LDS: U_T[b][n] and V_T[a][n], k(=n)-contiguous, rows padded to 72 bf16
// (16B-aligned, bank-spread) -> every fragment is one ds_read_b128.
// M=a, N=b: C/D col=lane&15=b (verified mapping) -> coalesced 64B stores.
// Tables generated with the validated closed-form eval (absmax 0.0039).
// ---------------------------------------------------------------------------
__global__ __launch_bounds__(256) void s4d_main(
    const float* __restrict__ par, const float* __restrict__ Dv,
    float* __restrict__ out)
{
    __shared__ __align__(16) float s_par[N_STATE][8];      // 2 KB
    __shared__ __align__(16) short s_u[4 * 64 * 72];       // 36864 B
    __shared__ __align__(16) short s_v[4 * 32 * 72];       // 18432 B

    const int d = blockIdx.x;
    const int t = threadIdx.x;

    if (t < 64) {
        const float4* g = (const float4*)(par + ((size_t)d * 64 + t) * PAR_STRIDE);
        *(float4*)&s_par[t][0] = g[0];
        *(float4*)&s_par[t][4] = g[1];
    }
    __syncthreads();

    // ---- U generation: thread owns b = t&63, n-range 16*(t>>6) + [0,16) ----
    {
        const int b = t & 63, g = t >> 6;
        const float lf = (float)b;
        #pragma unroll
        for (int half = 0; half < 2; ++half) {
            short8 prh, prl, pih, pil;
            #pragma unroll
            for (int nn = 0; nn < 8; ++nn) {
                const int n = (g << 4) + (half << 3) + nn;
                const float th_hi = s_par[n][0], th_lo = s_par[n][1];
                const float ph0   = s_par[n][2], la_hi = s_par[n][3];
                const float la_lo = s_par[n][4], lw    = s_par[n][5];
                float amp = exp2f(fmaf(lf, la_hi, fmaf(lf, la_lo, lw)));
                float f1  = __builtin_amdgcn_fractf(lf * th_hi);  // exact prod
                float ph  = __builtin_amdgcn_fractf(f1 + fmaf(lf, th_lo, ph0));
                float zr  = amp * __builtin_amdgcn_cosf(ph);
                float zi  = amp * __builtin_amdgcn_sinf(ph);
                unsigned short rh = bf16_rne(zr);
                unsigned short rl = bf16_rne(zr - bf16_f(rh));
                float niz = -zi;                                  // fold -Im*Im
                unsigned short ih = bf16_rne(niz);
                unsigned short il = bf16_rne(niz - bf16_f(ih));
                prh[nn] = (short)rh; prl[nn] = (short)rl;
                pih[nn] = (short)ih; pil[nn] = (short)il;
            }
            const int base = b * 72 + (g << 4) + (half << 3);
            *(short8*)&s_u[0 * 4608 + base] = prh;
            *(short8*)&s_u[1 * 4608 + base] = prl;
            *(short8*)&s_u[2 * 4608 + base] = pih;
            *(short8*)&s_u[3 * 4608 + base] = pil;
        }
    }
    // ---- V generation: thread owns a = t&31, n-range 8*(t>>5) + [0,8) ----
    {
        const int a = t & 31, h = t >> 5;
        const float lf = (float)(a << 6);          // l = 64a  (< 2^11: exact)
        short8 prh, prl, pih, pil;
        #pragma unroll
        for (int nn = 0; nn < 8; ++nn) {
            const int n = (h << 3) + nn;
            const float th_hi = s_par[n][0], th_lo = s_par[n][1];
            const float la_hi = s_par[n][3], la_lo = s_par[n][4];
            float amp = exp2f(fmaf(lf, la_hi, lf * la_lo));       // lw = 0
            float f1  = __builtin_amdgcn_fractf(lf * th_hi);
            float ph  = __builtin_amdgcn_fractf(f1 + lf * th_lo); // ph0 = 0
            float vr  = amp * __builtin_amdgcn_cosf(ph);
            float vi  = amp * __builtin_amdgcn_sinf(ph);
            unsigned short rh = bf16_rne(vr);
            unsigned short rl = bf16_rne(vr - bf16_f(rh));
            unsigned short ih = bf16_rne(vi);
            unsigned short il = bf16_rne(vi - bf16_f(ih));
            prh[nn] = (short)rh; prl[nn] = (short)rl;
            pih[nn] = (short)ih; pil[nn] = (short)il;
        }
        const int base = a * 72 + (h << 3);
        *(short8*)&s_v[0 * 2304 + base] = prh;
        *(short8*)&s_v[1 * 2304 + base] = prl;
        *(short8*)&s_v[2 * 2304 + base] = pih;
        *(short8*)&s_v[3 * 2304 + base] = pil;
    }
    __syncthreads();

    // ---- MFMA: wave w owns b-tile [16w,16w+16); both a-tiles ----
    const int w    = t >> 6;
    const int lane = t & 63;
    const int col  = lane & 15;       // b_local (N) / a_local (M) per fragment
    const int grp  = lane >> 4;
    const int brow = (w << 4) + col;  // B-frag: U_T row

    f32x4 acc0 = {0.f, 0.f, 0.f, 0.f};
    f32x4 acc1 = {0.f, 0.f, 0.f, 0.f};

    #pragma unroll
    for (int ksp = 0; ksp < 2; ++ksp) {
        const int k0 = (ksp << 5) + (grp << 3);
        const int ub = brow * 72 + k0;
        const short8 urh = *(const short8*)&s_u[0 * 4608 + ub];
        const short8 url = *(const short8*)&s_u[1 * 4608 + ub];
        const short8 uih = *(const short8*)&s_u[2 * 4608 + ub];
        const short8 uil = *(const short8*)&s_u[3 * 4608 + ub];
        // a-tile 0 (rows 0..15)
        {
            const int vb = col * 72 + k0;
            const short8 vrh = *(const short8*)&s_v[0 * 2304 + vb];
            const short8 vrl = *(const short8*)&s_v[1 * 2304 + vb];
            const short8 vih = *(const short8*)&s_v[2 * 2304 + vb];
            const short8 vil = *(const short8*)&s_v[3 * 2304 + vb];
            acc0 = __builtin_amdgcn_mfma_f32_16x16x32_bf16(vrh, urh, acc0, 0, 0, 0);
            acc0 = __builtin_amdgcn_mfma_f32_16x16x32_bf16(vrh, url, acc0, 0, 0, 0);
            acc0 = __builtin_amdgcn_mfma_f32_16x16x32_bf16(vrl, urh, acc0, 0, 0, 0);
            acc0 = __builtin_amdgcn_mfma_f32_16x16x32_bf16(vih, uih, acc0, 0, 0, 0);
            acc0 = __builtin_amdgcn_mfma_f32_16x16x32_bf16(vih, uil, acc0, 0, 0, 0);
            acc0 = __builtin_amdgcn_mfma_f32_16x16x32_bf16(vil, uih, acc0, 0, 0, 0);
        }
        // a-tile 1 (rows 16..31)
        {
            const int vb = (16 + col) * 72 + k0;
            const short8 vrh = *(const short8*)&s_v[0 * 2304 + vb];
            const short8 vrl = *(const short8*)&s_v[1 * 2304 + vb];
            const short8 vih = *(const short8*)&s_v[2 * 2304 + vb];
            const short8 vil = *(const short8*)&s_v[3 * 2304 + vb];
            acc1 = __builtin_amdgcn_mfma_f32_16x16x32_bf16(vrh, urh, acc1, 0, 0, 0);
            acc1 = __builtin_amdgcn_mfma_f32_16x16x32_bf16(vrh, url, acc1, 0, 0, 0);
            acc1 = __builtin_amdgcn_mfma_f32_16x16x32_bf16(vrl, urh, acc1, 0, 0, 0);
            acc1 = __builtin_amdgcn_mfma_f32_16x16x32_bf16(vih, uih, acc1, 0, 0, 0);
            acc1 = __builtin_amdgcn_mfma_f32_16x16x32_bf16(vih, uil, acc1, 0, 0, 0);
            acc1 = __builtin_amdgcn_mfma_f32_16x16x32_bf16(vil, uih, acc1, 0, 0, 0);
        }
    }

    // ---- store: D[a][b] -> out[d*2048 + 64a + b]; col=lane&15 is b (C/D
    // verified mapping), row = (lane>>4)*4 + r is a. 16-lane 64B runs. ----
    float* __restrict__ op = out + (size_t)d * L_LEN;
    const int b = brow;
    #pragma unroll
    for (int r = 0; r < 4; ++r) {
        const int a0 = (grp << 2) + r;
        float v0 = acc0[r];
        if (r == 0 && t == 0) v0 += Dv[d];      // l == 0 skip term
        op[(a0 << 6) + b] = v0;
        const int a1 = a0 + 16;
        op[(a1 << 6) + b] = acc1[r];
    }
}

extern "C" void kernel_launch(void* const* d_in, const int* in_sizes, int n_in,
                              void* d_out, int out_size, void* d_ws, size_t ws_size,
                              hipStream_t stream) {
    const float* A_real = (const float*)d_in[0];
    const float* A_imag = (const float*)d_in[1];
    const float* B      = (const float*)d_in[2];
    const float* C      = (const float*)d_in[3];
    const float* Dv     = (const float*)d_in[4];
    const float* log_dt = (const float*)d_in[5];
    float* out = (float*)d_out;
    float* par = (float*)d_ws;               // 1024*64*8 floats = 2 MB
    (void)in_sizes; (void)n_in; (void)ws_size; (void)out_size;

    s4d_setup<<<dim3(D_MODEL * N_STATE / 256), dim3(256), 0, stream>>>(
        A_real, A_imag, B, C, log_dt, par);
    s4d_main<<<dim3(D_MODEL), dim3(256), 0, stream>>>(par, Dv, out);
}